// Round 6
// baseline (371.844 us; speedup 1.0000x reference)
//
#include <hip/hip_runtime.h>
#include <hip/hip_bf16.h>

// Problem constants
#define B_   8
#define LQ   1024
#define LK   8192
#define D_   256
#define DC   128
#define EPSF 1e-6f

typedef __attribute__((ext_vector_type(8))) short short8;   // 8 bf16 (4 VGPRs)
typedef __attribute__((ext_vector_type(4))) float floatx4;  // 4 fp32 acc

static __device__ __forceinline__ floatx4 mfma16(short8 a, short8 b, floatx4 c) {
    return __builtin_amdgcn_mfma_f32_16x16x32_bf16(a, b, c, 0, 0, 0);
}
static __device__ __forceinline__ float fast_rcp(float x)  { return __builtin_amdgcn_rcpf(x); }
static __device__ __forceinline__ float fast_sqrt(float x) { return __builtin_amdgcn_sqrtf(x); }
static __device__ __forceinline__ float fast_ln(float x)   { return 0.69314718056f * __builtin_amdgcn_logf(x); }

// async global->LDS, 16 B per lane; LDS dest = wave-uniform base + lane*16
static __device__ __forceinline__ void gl16(const void* g, void* l) {
    __builtin_amdgcn_global_load_lds(
        (const __attribute__((address_space(1))) unsigned int*)g,
        (__attribute__((address_space(3))) unsigned int*)l, 16, 0, 0);
}

// ---------------------------------------------------------------------------
// K1: G = W_up^T @ W_up (128x128) bf16 + Wt = W^T bf16 (128x256).
// Wt lives in d_out[0:64KB) — written here, read by k_prep, overwritten by
// k_main (stream-ordered). Unchanged from R5.
__global__ __launch_bounds__(512) void k_G(const float* __restrict__ W,
                                           __hip_bfloat16* __restrict__ G,
                                           __hip_bfloat16* __restrict__ Wt) {
    __shared__ float red[512];
    int c1 = blockIdx.x;
    int t = threadIdx.x, c2 = t & 127, h = t >> 7;   // h = d-quarter 0..3
    int d0 = h * 64;
    float a0 = 0.f, a1 = 0.f, a2 = 0.f, a3 = 0.f;
#pragma unroll 4
    for (int d = 0; d < 64; d += 4) {
        a0 += W[(size_t)(d0 + d + 0) * DC + c1] * W[(size_t)(d0 + d + 0) * DC + c2];
        a1 += W[(size_t)(d0 + d + 1) * DC + c1] * W[(size_t)(d0 + d + 1) * DC + c2];
        a2 += W[(size_t)(d0 + d + 2) * DC + c1] * W[(size_t)(d0 + d + 2) * DC + c2];
        a3 += W[(size_t)(d0 + d + 3) * DC + c1] * W[(size_t)(d0 + d + 3) * DC + c2];
    }
    red[t] = (a0 + a1) + (a2 + a3);
    if (t < 256) Wt[(size_t)c1 * D_ + t] = __float2bfloat16(W[(size_t)t * DC + c1]);
    __syncthreads();
    if (h == 0)
        G[c1 * DC + c2] =
            __float2bfloat16(red[c2] + red[128 + c2] + red[256 + c2] + red[384 + c2]);
}

// ---------------------------------------------------------------------------
// qproj body: q_proj = (q @ W_up) -> bf16, q_sq fused. (Unchanged from R5.)
static __device__ __forceinline__ void qproj_body(
        char* smem, int blk,
        const float* __restrict__ q, const __hip_bfloat16* __restrict__ Wt,
        __hip_bfloat16* __restrict__ qproj, float* __restrict__ q_sq) {
    __hip_bfloat16* sA = (__hip_bfloat16*)smem;          // [32][72]
    __hip_bfloat16* sB = sA + 32 * 72;                   // [128][72]
    int t = threadIdx.x, lane = t & 63, w = t >> 6;
    int quad = lane >> 4, li = lane & 15;
    int wm = w >> 1, wn = w & 1;
    int row0 = blk * 32;

    float psum[2] = {0.f, 0.f};
    floatx4 acc[4];
#pragma unroll
    for (int nt = 0; nt < 4; ++nt) acc[nt] = (floatx4){0.f, 0.f, 0.f, 0.f};

    for (int kc4 = 0; kc4 < 4; ++kc4) {
#pragma unroll
        for (int it = 0; it < 2; ++it) {
            int idx = it * 256 + t;
            int r = idx >> 4, pos = idx & 15;
            float4 v = *(const float4*)(q + (size_t)(row0 + r) * D_ + kc4 * 64 + pos * 4);
            psum[it] += v.x * v.x + v.y * v.y + v.z * v.z + v.w * v.w;
            __hip_bfloat16* dst = &sA[r * 72 + pos * 4];
            dst[0] = __float2bfloat16(v.x); dst[1] = __float2bfloat16(v.y);
            dst[2] = __float2bfloat16(v.z); dst[3] = __float2bfloat16(v.w);
        }
#pragma unroll
        for (int it = 0; it < 4; ++it) {
            int e = it * 256 + t;          // [0,1024): 128 rows x 8 chunks
            int c = e >> 3, ch = e & 7;
            *(uint4*)&sB[c * 72 + ch * 8] =
                *(const uint4*)(Wt + (size_t)c * D_ + kc4 * 64 + ch * 8);
        }
        __syncthreads();
        short8 af[2];
#pragma unroll
        for (int ks = 0; ks < 2; ++ks)
            af[ks] = *(const short8*)&sA[(wm * 16 + li) * 72 + ks * 32 + quad * 8];
#pragma unroll
        for (int nt = 0; nt < 4; ++nt)
#pragma unroll
            for (int ks = 0; ks < 2; ++ks) {
                short8 bf = *(const short8*)&sB[((wn * 4 + nt) * 16 + li) * 72 + ks * 32 + quad * 8];
                acc[nt] = mfma16(af[ks], bf, acc[nt]);
            }
        __syncthreads();
    }
#pragma unroll
    for (int nt = 0; nt < 4; ++nt)
#pragma unroll
        for (int r = 0; r < 4; ++r) {
            int row = wm * 16 + quad * 4 + r;
            qproj[(size_t)(row0 + row) * DC + (wn * 4 + nt) * 16 + li] =
                __float2bfloat16(acc[nt][r]);
        }
#pragma unroll
    for (int it = 0; it < 2; ++it) {
        float s = psum[it];
        s += __shfl_xor(s, 1); s += __shfl_xor(s, 2);
        s += __shfl_xor(s, 4); s += __shfl_xor(s, 8);
        if (li == 0) q_sq[row0 + it * 16 + w * 4 + quad] = s;
    }
}

// ---------------------------------------------------------------------------
// dq_ksq body: dequant 64 rows -> kc (global) + LDS; k_sq via MFMA row-dot.
// (Unchanged from R5.)
static __device__ __forceinline__ void dq_body(
        char* smem, int blk,
        const int* __restrict__ kq, const float* __restrict__ kscale,
        const float* __restrict__ kzero, const __hip_bfloat16* __restrict__ G,
        __hip_bfloat16* __restrict__ kc, float* __restrict__ k_sq) {
    __hip_bfloat16* sK = (__hip_bfloat16*)smem;          // [64][132]
    int t = threadIdx.x, lane = t & 63, w = t >> 6;
    int quad = lane >> 4, li = lane & 15;
    int b = blk >> 7, l0 = (blk & 127) * 64;

    const int4* codes = (const int4*)(kq + ((size_t)b * LK + l0) * DC);
    int col = (t & 31) * 4;
    float4 sc = *(const float4*)(kscale + b * DC + col);
    float4 zp = *(const float4*)(kzero + b * DC + col);
    __hip_bfloat16* kco = kc + ((size_t)b * LK + l0) * DC;
#pragma unroll
    for (int it = 0; it < 8; ++it) {
        int idx = it * 256 + t;            // [0,2048)
        int r = idx >> 5;
        int4 c4 = codes[idx];
        __hip_bfloat16 tmp[4];
        tmp[0] = __float2bfloat16(sc.x * ((float)c4.x - zp.x));
        tmp[1] = __float2bfloat16(sc.y * ((float)c4.y - zp.y));
        tmp[2] = __float2bfloat16(sc.z * ((float)c4.z - zp.z));
        tmp[3] = __float2bfloat16(sc.w * ((float)c4.w - zp.w));
        *(uint2*)&sK[r * 132 + col] = *(const uint2*)tmp;
        *(uint2*)(kco + idx * 4)    = *(const uint2*)tmp;
    }
    __syncthreads();

    short8 af[4];
#pragma unroll
    for (int ks = 0; ks < 4; ++ks)
        af[ks] = *(const short8*)&sK[(w * 16 + li) * 132 + ks * 32 + quad * 8];
    float s4[4] = {0.f, 0.f, 0.f, 0.f};
#pragma unroll
    for (int nt = 0; nt < 8; ++nt) {
        floatx4 a0 = (floatx4){0.f, 0.f, 0.f, 0.f};
#pragma unroll
        for (int ks = 0; ks < 4; ++ks) {
            short8 bf = *(const short8*)(G + (size_t)(nt * 16 + li) * DC + ks * 32 + quad * 8);
            a0 = mfma16(af[ks], bf, a0);
        }
        int c2 = nt * 16 + li;
#pragma unroll
        for (int r = 0; r < 4; ++r)
            s4[r] += a0[r] * __bfloat162float(sK[(w * 16 + quad * 4 + r) * 132 + c2]);
    }
#pragma unroll
    for (int r = 0; r < 4; ++r) {
        float v = s4[r];
        v += __shfl_xor(v, 1); v += __shfl_xor(v, 2);
        v += __shfl_xor(v, 4); v += __shfl_xor(v, 8);
        if (li == 0)
            k_sq[(size_t)b * LK + l0 + w * 16 + quad * 4 + r] = v;
    }
}

// ---------------------------------------------------------------------------
// K2 fused prep (unchanged): blocks [0,256) qproj, [256,1280) dq_ksq.
__global__ __launch_bounds__(256) void k_prep(const float* __restrict__ q,
                                              const __hip_bfloat16* __restrict__ Wt,
                                              __hip_bfloat16* __restrict__ qproj,
                                              float* __restrict__ q_sq,
                                              const int* __restrict__ kq,
                                              const float* __restrict__ kscale,
                                              const float* __restrict__ kzero,
                                              const __hip_bfloat16* __restrict__ G,
                                              __hip_bfloat16* __restrict__ kc,
                                              float* __restrict__ k_sq) {
    __shared__ __align__(16) char smem[23040];   // max(qproj 23040, dq 16896)
    if (blockIdx.x < 256)
        qproj_body(smem, blockIdx.x, q, Wt, qproj, q_sq);
    else
        dq_body(smem, blockIdx.x - 256, kq, kscale, kzero, G, kc, k_sq);
}

// ---------------------------------------------------------------------------
// K3: main — SLAB REBUILD. Block = 32 m-rows x 2048 n (one batch quarter):
//  * A (32x128 of qproj) held in REGISTERS (af[2][4]) — no A staging at all.
//  * kc streamed as 32 tiles of 64 rows (16 KB) via gl16 + XOR swizzle into
//    a 2-buffer LDS; loop shape {stage(t+1); compute+epi(t); barrier} — ONE
//    barrier per tile and the staged loads' latency is hidden UNDER compute,
//    not exposed at the barrier (R4/R5 issued loads right before the drain).
//  * acc is 8 VGPR (2 m-frags x floatx4) -> ~70 VGPR total, big scheduler
//    headroom at 4 blocks/CU (LDS 32 KB).
//  * epilogue register-direct: thread owns 4 consecutive n per m-frag ->
//    nontemporal float4; block's writes = 32 sequential row-streams.
//  * XCD pin b=blk&7: kc[b] quarter (512 KB) L2-resident, reused by the 32
//    consecutive m-slab blocks on that XCD.
__global__ __launch_bounds__(256, 4) void k_main(const __hip_bfloat16* __restrict__ qproj,
                                                 const __hip_bfloat16* __restrict__ kc,
                                                 const float* __restrict__ q_sq,
                                                 const float* __restrict__ k_sq,
                                                 float* __restrict__ out) {
    __shared__ __align__(16) char smem[2 * 16384];   // 2 bufs x 64 rows x 256 B
    int t = threadIdx.x, lane = t & 63, w = t >> 6;
    int quad = lane >> 4, li = lane & 15;
    int blk = blockIdx.x;
    int b     = blk & 7;               // XCD-pinned batch (1024 % 8 == 0)
    int u     = blk >> 3;              // 0..127
    int m0    = (u & 31) << 5;         // 32-row m-slab (m fastest within XCD)
    int nbase = (u >> 5) << 11;        // n-quarter: 0,2048,4096,6144

    const char* kcb = (const char*)kc + ((size_t)b * LK) * 256;   // 256 B rows

    // ---- A fragments in registers: rows m0 + mf*16 + li, k = ks*32+quad*8
    short8 af[2][4];
#pragma unroll
    for (int mf = 0; mf < 2; ++mf)
#pragma unroll
        for (int ks = 0; ks < 4; ++ks)
            af[mf][ks] = *(const short8*)((const char*)qproj
                + ((size_t)b * LQ + m0 + mf * 16 + li) * 256 + ks * 64 + quad * 16);

    // ---- hoisted per-lane q terms and output row bases
    float qs[2], omq[2];
    float* orow[2];
#pragma unroll
    for (int mf = 0; mf < 2; ++mf) {
        qs[mf]  = q_sq[(size_t)b * LQ + m0 + mf * 16 + li];
        omq[mf] = 1.f - fminf(qs[mf], 1.f - EPSF);
        orow[mf] = out + ((size_t)b * LQ + m0 + mf * 16 + li) * (size_t)LK;
    }
    const float* ksqb = k_sq + (size_t)b * LK;

    // ---- staging lane constants: slot(row,ch) <- global chunk ch^(row&7)
    int loff[4];
#pragma unroll
    for (int it = 0; it < 4; ++it) {
        int sr = w * 16 + it * 4 + (lane >> 4);
        loff[it] = sr * 256 + ((((lane & 15) ^ (sr & 7))) << 4);
    }

    auto stage = [&](int tile, int buf) {
        size_t nb = ((size_t)(nbase + tile * 64)) << 8;
        char* db = smem + (buf << 14);
#pragma unroll
        for (int it = 0; it < 4; ++it)
            gl16(kcb + nb + loff[it], db + ((w * 16 + it * 4) << 8));
    };

    stage(0, 0);
    __syncthreads();                       // drain tile 0

    for (int tl = 0; tl < 32; ++tl) {
        if (tl + 1 < 32) stage(tl + 1, (tl + 1) & 1);   // issue EARLY (hidden)

        const char* sb = smem + ((tl & 1) << 14);
        floatx4 acc[2];
        acc[0] = (floatx4){0.f, 0.f, 0.f, 0.f};
        acc[1] = (floatx4){0.f, 0.f, 0.f, 0.f};
#pragma unroll
        for (int ks = 0; ks < 4; ++ks) {
            // B rows = n (w*16+li), swizzled chunk; shared by both m-frags
            short8 bf = *(const short8*)(sb + (w * 16 + li) * 256
                                         + ((((ks * 4 + quad) ^ (li & 7))) << 4));
            acc[0] = mfma16(bf, af[0][ks], acc[0]);   // D: row=n-local, col=m
            acc[1] = mfma16(bf, af[1][ks], acc[1]);
        }

        // epilogue: thread -> out[m0+mf*16+li][n_t .. n_t+3]
        int n_t = nbase + tl * 64 + w * 16 + quad * 4;
        floatx4 k4 = *(const floatx4*)(ksqb + n_t);
        floatx4 kn;
#pragma unroll
        for (int r = 0; r < 4; ++r)
            kn[r] = 1.f - fminf(k4[r], 1.f - EPSF);
#pragma unroll
        for (int mf = 0; mf < 2; ++mf) {
            floatx4 o;
#pragma unroll
            for (int r = 0; r < 4; ++r) {
                float diff  = fmaxf(qs[mf] + k4[r] - 2.f * acc[mf][r], 0.f);
                float delta = 2.f * diff * fast_rcp(omq[mf] * kn[r] + EPSF);
                float sq    = fast_sqrt(delta * (delta + 2.f));
                o[r] = fast_ln(1.f + delta + sq);
            }
            __builtin_nontemporal_store(o, (floatx4*)(orow[mf] + n_t));
        }
        __syncthreads();   // tile tl reads done AND tile tl+1 writes landed
    }
}

// ---------------------------------------------------------------------------
extern "C" void kernel_launch(void* const* d_in, const int* in_sizes, int n_in,
                              void* d_out, int out_size, void* d_ws, size_t ws_size,
                              hipStream_t stream) {
    const float* q      = (const float*)d_in[0];
    const int*   kq     = (const int*)d_in[1];
    const float* kscale = (const float*)d_in[2];
    const float* kzero  = (const float*)d_in[3];
    const float* W      = (const float*)d_in[4];
    float* out = (float*)d_out;

    // workspace layout (19.2 MB total, unchanged)
    char* ws = (char*)d_ws;
    __hip_bfloat16* qproj = (__hip_bfloat16*)(ws);                 // 2,097,152 B
    __hip_bfloat16* kc    = (__hip_bfloat16*)(ws + 2097152);       // 16,777,216 B
    __hip_bfloat16* G     = (__hip_bfloat16*)(ws + 18874368);      //    32,768 B
    float*          q_sq  = (float*)(ws + 18907136);               //    32,768 B
    float*          k_sq  = (float*)(ws + 18939904);               //   262,144 B
    // Wt scratch = first 64 KB of OUT: k_G writes, k_prep reads, k_main
    // overwrites (stream-ordered).
    __hip_bfloat16* Wt    = (__hip_bfloat16*)out;

    k_G    <<<128, 512, 0, stream>>>(W, G, Wt);
    k_prep <<<1280, 256, 0, stream>>>(q, Wt, qproj, q_sq, kq, kscale, kzero, G, kc, k_sq);
    k_main <<<1024, 256, 0, stream>>>(qproj, kc, q_sq, k_sq, out);
}